// Round 9
// baseline (820.387 us; speedup 1.0000x reference)
//
#include <hip/hip_runtime.h>
#include <hip/hip_bf16.h>
#include <math.h>

#define HH 10
#define DD 256
#define SPB 4      // segments per block (4 waves, fully independent)
#define CHUNK 64   // nodes per two-phase chunk (= wave size)

// off[g] = first index with seg[i] >= g; off[G] = n. Handles empty segments.
__global__ void seg_offsets_kernel(const int* __restrict__ seg, int n, int G,
                                   int* __restrict__ off) {
  int i = blockIdx.x * blockDim.x + threadIdx.x;
  if (i >= n) return;
  int cur = seg[i];
  int prev = (i == 0) ? -1 : seg[i - 1];
  for (int g = prev + 1; g <= cur; ++g) off[g] = i;
  if (i == n - 1) {
    for (int g = cur + 1; g <= G; ++g) off[g] = n;
  }
}

__device__ __forceinline__ float readlane_f(float v, int srclane) {
  return __int_as_float(__builtin_amdgcn_readlane(__float_as_int(v), srclane));
}

// One wave per segment (4 independent waves per block). Per chunk of <=64
// nodes: phase 1 = lane-per-node serial dot (W via scalar loads, no
// cross-lane reduction); phase 2 = lane-per-4-columns accumulation with w
// broadcast via v_readlane. No LDS, no __syncthreads.
__global__ __launch_bounds__(256) void seg_pool_kernel(
    const float* __restrict__ feat, const float* __restrict__ W,
    const float* __restrict__ b, const int* __restrict__ off,
    float* __restrict__ out, int G) {
  const int lane = threadIdx.x & 63;
  const int g = blockIdx.x * SPB + (threadIdx.x >> 6);
  if (g >= G) return;

  float acc[HH][4];
  float dsum[HH];
#pragma unroll
  for (int k = 0; k < HH; ++k) {
    dsum[k] = 0.f;
    acc[k][0] = acc[k][1] = acc[k][2] = acc[k][3] = 0.f;
  }

  const int s = off[g];
  const int e = off[g + 1];

  for (int base = s; base < e; base += CHUNK) {
    const int mc = min(CHUNK, e - base);

    // ---- phase 1: lane owns one node; compute x[k] = f[node] . W[:,k] ----
    const int myrow = base + ((lane < mc) ? lane : (mc - 1));
    const float* fr = feat + (size_t)myrow * DD;

    float x[HH];
#pragma unroll
    for (int k = 0; k < HH; ++k) x[k] = 0.f;

    for (int d4 = 0; d4 < DD / 4; ++d4) {
      const float4 f = *reinterpret_cast<const float4*>(fr + d4 * 4);
      // W rows 4*d4 .. 4*d4+3, all heads: 40 consecutive floats,
      // wave-uniform address -> scalar loads + v_fmac with SGPR operand.
      const float* wp = W + (size_t)d4 * 4 * HH;
#pragma unroll
      for (int k = 0; k < HH; ++k) {
        float t = fmaf(f.x, wp[0 * HH + k], x[k]);
        t = fmaf(f.y, wp[1 * HH + k], t);
        t = fmaf(f.z, wp[2 * HH + k], t);
        t = fmaf(f.w, wp[3 * HH + k], t);
        x[k] = t;
      }
    }

    // sigmoid, fully lane-parallel (each lane = its own node)
    float w[HH];
#pragma unroll
    for (int k = 0; k < HH; ++k) {
      float xx = x[k] + b[k];
      w[k] = __builtin_amdgcn_rcpf(1.f + __expf(-xx));
    }

    // ---- phase 2: lane owns 4 columns; accumulate over chunk nodes ----
    // Rows are L1/L2-hot (phase 1 just streamed them on this CU).
    const float* fp2 = feat + (size_t)base * DD + lane * 4;
    for (int n = 0; n < mc; ++n) {
      const float4 f = *reinterpret_cast<const float4*>(fp2 + (size_t)n * DD);
#pragma unroll
      for (int k = 0; k < HH; ++k) {
        const float wk = readlane_f(w[k], n);   // uniform broadcast, no LDS
        dsum[k] += wk;
        acc[k][0] = fmaf(wk, f.x, acc[k][0]);
        acc[k][1] = fmaf(wk, f.y, acc[k][1]);
        acc[k][2] = fmaf(wk, f.z, acc[k][2]);
        acc[k][3] = fmaf(wk, f.w, acc[k][3]);
      }
    }
  }

  // keys[g][k][d] = num/denom ; 0 * rcp(0) = NaN matches reference on
  // empty segments.
  float* op = out + ((size_t)g * HH) * DD + lane * 4;
#pragma unroll
  for (int k = 0; k < HH; ++k) {
    float r = __builtin_amdgcn_rcpf(dsum[k]);
    float4 o = make_float4(acc[k][0] * r, acc[k][1] * r,
                           acc[k][2] * r, acc[k][3] * r);
    *reinterpret_cast<float4*>(op + (size_t)k * DD) = o;
  }
}

extern "C" void kernel_launch(void* const* d_in, const int* in_sizes, int n_in,
                              void* d_out, int out_size, void* d_ws, size_t ws_size,
                              hipStream_t stream) {
  const float* feat = (const float*)d_in[0];
  const float* W    = (const float*)d_in[1];
  const float* b    = (const float*)d_in[2];
  const int*   seg  = (const int*)d_in[3];
  float* out = (float*)d_out;

  const int H_ = in_sizes[2];             // 10
  const int D_ = in_sizes[1] / H_;        // 256
  const int N  = in_sizes[0] / D_;        // 500000
  const int G  = out_size / (H_ * D_);    // 8192

  int* off = (int*)d_ws;                  // (G+1) ints of scratch

  seg_offsets_kernel<<<(N + 255) / 256, 256, 0, stream>>>(seg, N, G, off);
  seg_pool_kernel<<<(G + SPB - 1) / SPB, 256, 0, stream>>>(feat, W, b, off,
                                                           out, G);
}